// Round 13
// baseline (334.690 us; speedup 1.0000x reference)
//
#include <hip/hip_runtime.h>

typedef _Float16 f16x8 __attribute__((ext_vector_type(8)));
typedef __fp16 h16x2 __attribute__((ext_vector_type(2)));
typedef float f32x4 __attribute__((ext_vector_type(4)));
typedef unsigned short u16x4 __attribute__((ext_vector_type(4)));

#define NB 4
#define NSEQ 2048
#define NH 16
#define HDIM 64
#define DM 1024
#define MROWS (NB * NSEQ) /* 8192 */

#define AS1 __attribute__((address_space(1)))
#define AS3 __attribute__((address_space(3)))

__device__ __forceinline__ float exp2_fast(float x) {
  float r; asm("v_exp_f32 %0, %1" : "=v"(r) : "v"(x)); return r;
}

__device__ __forceinline__ unsigned short f2h(float f) {
  _Float16 h = (_Float16)f; // v_cvt_f16_f32, RNE
  union { _Float16 h; unsigned short u; } v; v.h = h;
  return v.u;
}

// One dispatch converts x (2M float4) + the four 1024x1024 weights (4 x 256K).
__global__ void cvt_all_kernel(const float* __restrict__ x, const float* __restrict__ w0,
                               const float* __restrict__ w1, const float* __restrict__ w2,
                               const float* __restrict__ w3, unsigned short* __restrict__ xo,
                               unsigned short* __restrict__ o0, unsigned short* __restrict__ o1,
                               unsigned short* __restrict__ o2, unsigned short* __restrict__ o3) {
  const int id = blockIdx.x * blockDim.x + threadIdx.x;   // 0 .. 3.25M-1
  const float* src; unsigned short* dst; int i;
  if (id < (MROWS * DM) / 4) { src = x; dst = xo; i = id; }
  else {
    const int id2 = id - (MROWS * DM) / 4;
    const int w = id2 >> 18;             // 0..3 (256K float4 per weight)
    i = id2 & 262143;
    switch (w) {
      case 0: src = w0; dst = o0; break;
      case 1: src = w1; dst = o1; break;
      case 2: src = w2; dst = o2; break;
      default: src = w3; dst = o3; break;
    }
  }
  const float4 v = ((const float4*)src)[i];
  u16x4 o;
  o.x = f2h(v.x); o.y = f2h(v.y); o.z = f2h(v.z); o.w = f2h(v.w);
  ((u16x4*)dst)[i] = o;
}

// Shared GEMM body: C[8192,1024] = A[8192,1024] * Bw[1024,1024]^T,
// epilogue (acc+bias)*scale. m97-style: 128x128 tile, BK=32, 4 waves each
// 64x64 (4x4 of 16x16x32 MFMA). XCD-chunked block swizzle: per-XCD working
// set = A-chunk 2MB + B 2MB (~one L2).
template<int OUT_F16>
__device__ __forceinline__
void gemm_body(const unsigned short* __restrict__ A, const unsigned short* __restrict__ Bw,
               const float* __restrict__ bias, void* __restrict__ Cv, float scale,
               unsigned short* As, unsigned short* Bs) {
  const int tid = threadIdx.x, lane = tid & 63, wave = tid >> 6;
  const int g = lane >> 4, c = lane & 15;
  const int orig = blockIdx.y * 8 + blockIdx.x;
  const int wg = (orig & 7) * 64 + (orig >> 3);   // bijective xcd-chunk remap
  const int m0 = (wg >> 3) * 128, n0 = (wg & 7) * 128;
  const int wm = (wave >> 1) * 64, wn = (wave & 1) * 64;
  f32x4 acc[4][4] = {};
  for (int kt = 0; kt < 1024; kt += 32) {
#pragma unroll
    for (int p = 0; p < 2; ++p) {
      const int idx = p * 256 + tid;
      const int row = idx >> 2, col = (idx & 3) * 8;
      __builtin_amdgcn_global_load_lds(
          (const AS1 void*)(A + (size_t)(m0 + row) * 1024 + kt + col),
          (AS3 void*)(As + idx * 8), 16, 0, 0);
      __builtin_amdgcn_global_load_lds(
          (const AS1 void*)(Bw + (size_t)(n0 + row) * 1024 + kt + col),
          (AS3 void*)(Bs + idx * 8), 16, 0, 0);
    }
    __syncthreads();
    f16x8 af[4], bfr[4];
#pragma unroll
    for (int i = 0; i < 4; ++i) af[i] = *(const f16x8*)(As + (wm + i * 16 + c) * 32 + g * 8);
#pragma unroll
    for (int i = 0; i < 4; ++i) bfr[i] = *(const f16x8*)(Bs + (wn + i * 16 + c) * 32 + g * 8);
#pragma unroll
    for (int i = 0; i < 4; ++i)
#pragma unroll
      for (int j = 0; j < 4; ++j)
        acc[i][j] = __builtin_amdgcn_mfma_f32_16x16x32_f16(af[i], bfr[j], acc[i][j], 0, 0, 0);
    __syncthreads();
  }
#pragma unroll
  for (int i = 0; i < 4; ++i)
#pragma unroll
    for (int j = 0; j < 4; ++j)
#pragma unroll
      for (int r = 0; r < 4; ++r) {
        const int row = m0 + wm + i * 16 + g * 4 + r;
        const int col = n0 + wn + j * 16 + c;
        const float v = (acc[i][j][r] + bias[col]) * scale;
        if (OUT_F16) ((unsigned short*)Cv)[(size_t)row * 1024 + col] = f2h(v);
        else         ((float*)Cv)[(size_t)row * 1024 + col] = v;
      }
}

// Q, K, V projections in ONE dispatch: blockIdx.z selects weight/bias/output.
__global__ __launch_bounds__(256)
void gemm_qkv(const unsigned short* __restrict__ A,
              const unsigned short* __restrict__ W0, const unsigned short* __restrict__ W1,
              const unsigned short* __restrict__ W2,
              const float* __restrict__ b0, const float* __restrict__ b1,
              const float* __restrict__ b2,
              unsigned short* __restrict__ C0, unsigned short* __restrict__ C1,
              unsigned short* __restrict__ C2, float qscale) {
  __shared__ unsigned short As[128 * 32];
  __shared__ unsigned short Bs[128 * 32];
  const unsigned short* Bw; const float* bias; unsigned short* C; float scale;
  switch (blockIdx.z) {
    case 0:  Bw = W0; bias = b0; C = C0; scale = qscale; break;
    case 1:  Bw = W1; bias = b1; C = C1; scale = 1.f; break;
    default: Bw = W2; bias = b2; C = C2; scale = 1.f; break;
  }
  gemm_body<1>(A, Bw, bias, C, scale, As, Bs);
}

__global__ __launch_bounds__(256)
void gemm_out(const unsigned short* __restrict__ A, const unsigned short* __restrict__ Bw,
              const float* __restrict__ bias, float* __restrict__ Cv) {
  __shared__ unsigned short As[128 * 32];
  __shared__ unsigned short Bs[128 * 32];
  gemm_body<0>(A, Bw, bias, Cv, 1.f, As, Bs);
}

// Flash-style signed-softmax attention, swapped-operand structure.
// 4 waves x 64 q-rows; 2 waves/SIMD (regs ~215; 3 forces spills — r10).
// Round-13: KV SUPER-TILE = 128 (2 x 64 sub-tiles per barrier) — halves the
// barrier count (32 -> 16) and the per-barrier vmcnt/lgkmcnt drain + sync
// skew, the main addressable stall at 2 waves/SIMD. LDS 68KB (2 blocks/CU).
// Staging: stageK(t+1, both subs) + loadV(sub0) at top; writeV(sub0) +
// loadV(sub1) between sub-computes; writeV(sub1) before the barrier. Write
// side always targets buffer cur^1 whose readers were fenced by the previous
// barrier -> no wave-skew hazard.
// QK^T as mfma(K,Q) -> lane owns q = lane&15: softmax fully in-register.
// Fixed-shift softmax: P = sign(S)*exp2(|S|-18). Denominator via per-lane
// partials, cross-lane reduced once at the end.
// PV: O^T = mfma(V^T-frag, P-frag); kv<->slot bijection keeps P lane-local.
// Grid (8,64) XCD-chunked (chunk=64): each XCD's 64 blocks share 8 (b,h)
// panels (K/V working set 4MB = one L2).
__global__ __launch_bounds__(256, 2)
void attn_kernel(const unsigned short* __restrict__ Qg, const unsigned short* __restrict__ Kg,
                 const unsigned short* __restrict__ Vg, unsigned short* __restrict__ Og) {
  __shared__ __align__(16) unsigned short Kl[2][2 * 64 * 64];  // [buf][sub*4096+..]
  __shared__ __align__(16) unsigned short Vt[2][2 * 64 * 72];  // [buf][sub*4608+..]
  const int tid = threadIdx.x, lane = tid & 63, wave = tid >> 6;
  const int g = lane >> 4, c = lane & 15;
  const int orig = blockIdx.y * 8 + blockIdx.x;
  const int wg = (orig & 7) * 64 + (orig >> 3);   // bijective xcd-chunk remap
  const int qblk = wg & 7, bh = wg >> 3;
  const int b = bh >> 4, h = bh & 15;
  const int q0 = qblk * 256 + wave * 64;
  const size_t rb = (size_t)b * NSEQ;
  const int hc = h * HDIM;
  const int NT2 = NSEQ / 128;   // 16 super-tiles

  // K staging: LDS linear o = p*2048 + tid*8 holds K[kv=o>>6][d=(o&63)^((kv&7)*8)]
  const int k_kvo = tid >> 3;
  const int k_d   = (((tid & 7) ^ ((tid >> 3) & 7)) * 8);
  // V staging (row-pairs): thread handles rows {2i, 2i+1}, cols [ds8, ds8+8)
  // where i = tid&31, ds8 = (tid>>5)*8. Writes b32 pairs at column pi(2i):
  // pi = (b5)(b3 b2)(b4)(b1 b0) keeps low 2 bits -> pi(2i)+1 = pi(2i+1).
  const int v_i = tid & 31;
  const int v_ds8 = (tid >> 5) * 8;
  const int v_r0 = 2 * v_i;
  const int pv2 = (v_r0 & 32) | (((v_r0 >> 2) & 3) << 3) | (((v_r0 >> 4) & 1) << 2) | (v_r0 & 3);

  // Q fragments (SCALE*log2e folded in by the Q-GEMM epilogue)
  f16x8 qf[4][2];
#pragma unroll
  for (int m = 0; m < 4; ++m)
#pragma unroll
    for (int kb2 = 0; kb2 < 2; ++kb2)
      qf[m][kb2] = *(const f16x8*)(Qg + (rb + q0 + m * 16 + c) * DM + hc + kb2 * 32 + g * 8);

  f32x4 oT[4][4] = {};               // [db][m]; C col = q = c, row = d = g*4+r
  float dpart[4] = {0.f, 0.f, 0.f, 0.f};
  f16x8 vreg[2];                     // rows 2i and 2i+1 of one sub-tile

  auto stageK = [&](int t, int buf) {   // stages BOTH subs of super-tile t
#pragma unroll
    for (int p = 0; p < 4; ++p) {
      const int kv = t * 128 + 32 * p + k_kvo;
      __builtin_amdgcn_global_load_lds(
          (const AS1 void*)(Kg + (rb + kv) * DM + hc + k_d),
          (AS3 void*)(&Kl[buf][p * 2048 + tid * 8]), 16, 0, 0);
    }
  };
  auto loadV = [&](int t, int sub) {
    const unsigned short* src = Vg + (rb + t * 128 + sub * 64 + v_r0) * DM + hc + v_ds8;
    vreg[0] = *(const f16x8*)(src);
    vreg[1] = *(const f16x8*)(src + DM);
  };
  auto writeV = [&](int buf, int sub) {
    unsigned short* base = &Vt[buf][sub * 4608];
    union { f16x8 v; unsigned short u[8]; } a, bb;
    a.v = vreg[0]; bb.v = vreg[1];
#pragma unroll
    for (int j = 0; j < 8; ++j) {
      union { unsigned short s[2]; unsigned u; } w;
      w.s[0] = a.u[j]; w.s[1] = bb.u[j];
      *(unsigned*)(base + (v_ds8 + j) * 72 + pv2) = w.u;
    }
  };

  // per-sub compute: r11 body (kf/vtf fragments + 4 m-blocks)
  auto compute_sub = [&](const unsigned short* KL, const unsigned short* VT) {
    f16x8 kf[2][4];
#pragma unroll
    for (int kb2 = 0; kb2 < 2; ++kb2)
#pragma unroll
      for (int nb = 0; nb < 4; ++nb)
        kf[kb2][nb] = *(const f16x8*)(KL + (nb * 16 + c) * 64 + (((kb2 * 32 + g * 8) ^ ((c & 7) * 8))));
    f16x8 vtf[2][4];
#pragma unroll
    for (int kb2 = 0; kb2 < 2; ++kb2)
#pragma unroll
      for (int db = 0; db < 4; ++db)
        vtf[kb2][db] = *(const f16x8*)(VT + (db * 16 + c) * 72 + kb2 * 32 + g * 8);

#pragma unroll
    for (int m = 0; m < 4; ++m) {
      f32x4 s[4] = {};
#pragma unroll
      for (int nb = 0; nb < 4; ++nb)
#pragma unroll
        for (int kb2 = 0; kb2 < 2; ++kb2)
          s[nb] = __builtin_amdgcn_mfma_f32_16x16x32_f16(kf[kb2][nb], qf[m][kb2], s[nb], 0, 0, 0);

      // slot (kb2,g,j) <-> kv = 32*kb2 + 16*(j>>2) + 4*g + (j&3)
      union PW { f16x8 v; h16x2 w[4]; } pf[2];
      float es0 = 0.f, es1 = 0.f;
#pragma unroll
      for (int nb = 0; nb < 4; ++nb) {
        float p[4];
#pragma unroll
        for (int r = 0; r < 4; ++r) {
          const float sv = s[nb][r];
          const float e = exp2_fast(fabsf(sv) - 18.0f);
          if (r & 1) es1 += e; else es0 += e;
          p[r] = copysignf(e, sv);   // sign(S)*softmax(|S|)
        }
        pf[nb >> 1].w[(nb & 1) * 2]     = __builtin_amdgcn_cvt_pkrtz(p[0], p[1]);
        pf[nb >> 1].w[(nb & 1) * 2 + 1] = __builtin_amdgcn_cvt_pkrtz(p[2], p[3]);
      }
      dpart[m] += es0 + es1;

#pragma unroll
      for (int db = 0; db < 4; ++db) {
        oT[db][m] = __builtin_amdgcn_mfma_f32_16x16x32_f16(vtf[0][db], pf[0].v, oT[db][m], 0, 0, 0);
        oT[db][m] = __builtin_amdgcn_mfma_f32_16x16x32_f16(vtf[1][db], pf[1].v, oT[db][m], 0, 0, 0);
      }
    }
  };

  // prologue: super-tile 0 into buffer 0
  stageK(0, 0);
  loadV(0, 0); writeV(0, 0);
  loadV(0, 1); writeV(0, 1);
  __syncthreads();

  for (int t = 0; t < NT2; ++t) {
    const int cur = t & 1;
    const int nxt = cur ^ 1;
    const bool more = (t + 1 < NT2);
    if (more) { stageK(t + 1, nxt); loadV(t + 1, 0); }

    compute_sub(&Kl[cur][0], &Vt[cur][0]);

    if (more) { writeV(nxt, 0); loadV(t + 1, 1); }

    compute_sub(&Kl[cur][4096], &Vt[cur][4608]);

    if (more) writeV(nxt, 1);
    __syncthreads();
  }

  // --- denominator reduce (once) + normalize + store ---
  // lane holds O[q = m*16+c][d = db*16 + g*4 + r]
#pragma unroll
  for (int m = 0; m < 4; ++m) {
    float d = dpart[m];
    d += __shfl_xor(d, 16);
    d += __shfl_xor(d, 32);
    const float inv = 1.f / d;
#pragma unroll
    for (int db = 0; db < 4; ++db) {
      h16x2 h01 = __builtin_amdgcn_cvt_pkrtz(oT[db][m][0] * inv, oT[db][m][1] * inv);
      h16x2 h23 = __builtin_amdgcn_cvt_pkrtz(oT[db][m][2] * inv, oT[db][m][3] * inv);
      union { h16x2 h; unsigned u; } a, bb; a.h = h01; bb.h = h23;
      union { uint2 u2; unsigned u[2]; } st;
      st.u[0] = a.u; st.u[1] = bb.u;
      *(uint2*)(Og + (rb + q0 + m * 16 + c) * DM + hc + db * 16 + g * 4) = st.u2;
    }
  }
}

extern "C" void kernel_launch(void* const* d_in, const int* in_sizes, int n_in,
                              void* d_out, int out_size, void* d_ws, size_t ws_size,
                              hipStream_t stream) {
  const float* x  = (const float*)d_in[0];
  const float* Wq = (const float*)d_in[1];
  const float* bq = (const float*)d_in[2];
  const float* Wk = (const float*)d_in[3];
  const float* bk = (const float*)d_in[4];
  const float* Wv = (const float*)d_in[5];
  const float* bv = (const float*)d_in[6];
  const float* Wo = (const float*)d_in[7];
  const float* bo = (const float*)d_in[8];
  float* out = (float*)d_out;

  // workspace layout (f16 elements), total ~75.5 MB
  unsigned short* xb  = (unsigned short*)d_ws;                 // 8192*1024
  unsigned short* wqb = xb  + (size_t)MROWS * DM;              // 1024*1024 each
  unsigned short* wkb = wqb + (size_t)DM * DM;
  unsigned short* wvb = wkb + (size_t)DM * DM;
  unsigned short* wob = wvb + (size_t)DM * DM;
  unsigned short* qb  = wob + (size_t)DM * DM;                 // 8192*1024 each
  unsigned short* kb  = qb  + (size_t)MROWS * DM;
  unsigned short* vb  = kb  + (size_t)MROWS * DM;
  unsigned short* ab  = xb;  // reuse x region for attention output (x dead by then)

  cvt_all_kernel<<<(MROWS * DM / 4 + 4 * DM * DM / 4) / 256, 256, 0, stream>>>(
      x, Wq, Wk, Wv, Wo, xb, wqb, wkb, wvb, wob);

  // logits computed in exp2 domain: fold HD^-0.5 * log2(e) into Q
  const float SC = 0.125f * 1.4426950408889634f;
  gemm_qkv<<<dim3(DM / 128, MROWS / 128, 3), 256, 0, stream>>>(
      xb, wqb, wkb, wvb, bq, bk, bv, qb, kb, vb, SC);

  attn_kernel<<<dim3(NSEQ / 256, NB * NH), 256, 0, stream>>>(qb, kb, vb, ab);

  gemm_out<<<dim3(DM / 128, MROWS / 128), 256, 0, stream>>>(ab, wob, bo, out);
}

// Round 14
// 192.129 us; speedup vs baseline: 1.7420x; 1.7420x over previous
//
#include <hip/hip_runtime.h>

typedef _Float16 f16x8 __attribute__((ext_vector_type(8)));
typedef __fp16 h16x2 __attribute__((ext_vector_type(2)));
typedef float f32x4 __attribute__((ext_vector_type(4)));
typedef unsigned short u16x4 __attribute__((ext_vector_type(4)));

#define NB 4
#define NSEQ 2048
#define NH 16
#define HDIM 64
#define DM 1024
#define MROWS (NB * NSEQ) /* 8192 */

#define AS1 __attribute__((address_space(1)))
#define AS3 __attribute__((address_space(3)))

__device__ __forceinline__ float exp2_fast(float x) {
  float r; asm("v_exp_f32 %0, %1" : "=v"(r) : "v"(x)); return r;
}

__device__ __forceinline__ unsigned short f2h(float f) {
  _Float16 h = (_Float16)f; // v_cvt_f16_f32, RNE
  union { _Float16 h; unsigned short u; } v; v.h = h;
  return v.u;
}

// One dispatch converts x (2M float4) + the four 1024x1024 weights (4 x 256K).
__global__ void cvt_all_kernel(const float* __restrict__ x, const float* __restrict__ w0,
                               const float* __restrict__ w1, const float* __restrict__ w2,
                               const float* __restrict__ w3, unsigned short* __restrict__ xo,
                               unsigned short* __restrict__ o0, unsigned short* __restrict__ o1,
                               unsigned short* __restrict__ o2, unsigned short* __restrict__ o3) {
  const int id = blockIdx.x * blockDim.x + threadIdx.x;   // 0 .. 3.25M-1
  const float* src; unsigned short* dst; int i;
  if (id < (MROWS * DM) / 4) { src = x; dst = xo; i = id; }
  else {
    const int id2 = id - (MROWS * DM) / 4;
    const int w = id2 >> 18;             // 0..3 (256K float4 per weight)
    i = id2 & 262143;
    switch (w) {
      case 0: src = w0; dst = o0; break;
      case 1: src = w1; dst = o1; break;
      case 2: src = w2; dst = o2; break;
      default: src = w3; dst = o3; break;
    }
  }
  const float4 v = ((const float4*)src)[i];
  u16x4 o;
  o.x = f2h(v.x); o.y = f2h(v.y); o.z = f2h(v.z); o.w = f2h(v.w);
  ((u16x4*)dst)[i] = o;
}

// Shared GEMM body: C[8192,1024] = A[8192,1024] * Bw[1024,1024]^T,
// epilogue (acc+bias)*scale. m97-style: 128x128 tile, BK=32, 4 waves each
// 64x64 (4x4 of 16x16x32 MFMA). XCD-chunked block swizzle: per-XCD working
// set = A-chunk 2MB + B 2MB (~one L2).
template<int OUT_F16>
__device__ __forceinline__
void gemm_body(const unsigned short* __restrict__ A, const unsigned short* __restrict__ Bw,
               const float* __restrict__ bias, void* __restrict__ Cv, float scale,
               unsigned short* As, unsigned short* Bs) {
  const int tid = threadIdx.x, lane = tid & 63, wave = tid >> 6;
  const int g = lane >> 4, c = lane & 15;
  const int orig = blockIdx.y * 8 + blockIdx.x;
  const int wg = (orig & 7) * 64 + (orig >> 3);   // bijective xcd-chunk remap
  const int m0 = (wg >> 3) * 128, n0 = (wg & 7) * 128;
  const int wm = (wave >> 1) * 64, wn = (wave & 1) * 64;
  f32x4 acc[4][4] = {};
  for (int kt = 0; kt < 1024; kt += 32) {
#pragma unroll
    for (int p = 0; p < 2; ++p) {
      const int idx = p * 256 + tid;
      const int row = idx >> 2, col = (idx & 3) * 8;
      __builtin_amdgcn_global_load_lds(
          (const AS1 void*)(A + (size_t)(m0 + row) * 1024 + kt + col),
          (AS3 void*)(As + idx * 8), 16, 0, 0);
      __builtin_amdgcn_global_load_lds(
          (const AS1 void*)(Bw + (size_t)(n0 + row) * 1024 + kt + col),
          (AS3 void*)(Bs + idx * 8), 16, 0, 0);
    }
    __syncthreads();
    f16x8 af[4], bfr[4];
#pragma unroll
    for (int i = 0; i < 4; ++i) af[i] = *(const f16x8*)(As + (wm + i * 16 + c) * 32 + g * 8);
#pragma unroll
    for (int i = 0; i < 4; ++i) bfr[i] = *(const f16x8*)(Bs + (wn + i * 16 + c) * 32 + g * 8);
#pragma unroll
    for (int i = 0; i < 4; ++i)
#pragma unroll
      for (int j = 0; j < 4; ++j)
        acc[i][j] = __builtin_amdgcn_mfma_f32_16x16x32_f16(af[i], bfr[j], acc[i][j], 0, 0, 0);
    __syncthreads();
  }
#pragma unroll
  for (int i = 0; i < 4; ++i)
#pragma unroll
    for (int j = 0; j < 4; ++j)
#pragma unroll
      for (int r = 0; r < 4; ++r) {
        const int row = m0 + wm + i * 16 + g * 4 + r;
        const int col = n0 + wn + j * 16 + c;
        const float v = (acc[i][j][r] + bias[col]) * scale;
        if (OUT_F16) ((unsigned short*)Cv)[(size_t)row * 1024 + col] = f2h(v);
        else         ((float*)Cv)[(size_t)row * 1024 + col] = v;
      }
}

// Q, K, V projections in ONE dispatch: blockIdx.z selects weight/bias/output.
__global__ __launch_bounds__(256)
void gemm_qkv(const unsigned short* __restrict__ A,
              const unsigned short* __restrict__ W0, const unsigned short* __restrict__ W1,
              const unsigned short* __restrict__ W2,
              const float* __restrict__ b0, const float* __restrict__ b1,
              const float* __restrict__ b2,
              unsigned short* __restrict__ C0, unsigned short* __restrict__ C1,
              unsigned short* __restrict__ C2, float qscale) {
  __shared__ unsigned short As[128 * 32];
  __shared__ unsigned short Bs[128 * 32];
  const unsigned short* Bw; const float* bias; unsigned short* C; float scale;
  switch (blockIdx.z) {
    case 0:  Bw = W0; bias = b0; C = C0; scale = qscale; break;
    case 1:  Bw = W1; bias = b1; C = C1; scale = 1.f; break;
    default: Bw = W2; bias = b2; C = C2; scale = 1.f; break;
  }
  gemm_body<1>(A, Bw, bias, C, scale, As, Bs);
}

__global__ __launch_bounds__(256)
void gemm_out(const unsigned short* __restrict__ A, const unsigned short* __restrict__ Bw,
              const float* __restrict__ bias, float* __restrict__ Cv) {
  __shared__ unsigned short As[128 * 32];
  __shared__ unsigned short Bs[128 * 32];
  gemm_body<0>(A, Bw, bias, Cv, 1.f, As, Bs);
}

// Flash-style signed-softmax attention, swapped-operand structure (round-9
// core, round-11 best config: 192.8us total, attn 102us).
// 4 waves x 64 q-rows: each wave's full-K/V LDS reads serve 64 q-rows.
// Per-m transient S keeps peak regs ~215 -> 2 waves/SIMD. Register ceiling
// is exact: 3 waves (r10) or duplicated compute bodies (r13) both spill
// catastrophically (WRITE_SIZE 0.016 -> 500-700 MB).
// QK^T as mfma(K,Q) -> lane owns q = lane&15: softmax fully in-register.
// Fixed-shift softmax: P = sign(S)*exp2(|S|-18). Denominator via per-lane
// partials, cross-lane reduced once at the end.
// PV: O^T = mfma(V^T-frag, P-frag); kv<->slot bijection keeps P lane-local.
// Grid (8,64) XCD-chunked (chunk=64): each XCD's 64 blocks share 8 (b,h)
// panels (K/V working set 4MB = one L2).
__global__ __launch_bounds__(256, 2)
void attn_kernel(const unsigned short* __restrict__ Qg, const unsigned short* __restrict__ Kg,
                 const unsigned short* __restrict__ Vg, unsigned short* __restrict__ Og) {
  __shared__ __align__(16) unsigned short Kl[2][64 * 64];
  __shared__ __align__(16) unsigned short Vt[2][64 * 72];
  const int tid = threadIdx.x, lane = tid & 63, wave = tid >> 6;
  const int g = lane >> 4, c = lane & 15;
  const int orig = blockIdx.y * 8 + blockIdx.x;
  const int wg = (orig & 7) * 64 + (orig >> 3);   // bijective xcd-chunk remap
  const int qblk = wg & 7, bh = wg >> 3;
  const int b = bh >> 4, h = bh & 15;
  const int q0 = qblk * 256 + wave * 64;
  const size_t rb = (size_t)b * NSEQ;
  const int hc = h * HDIM;
  const int NT = NSEQ / 64;

  // K staging: LDS linear o = p*2048 + tid*8 holds K[kv=o>>6][d=(o&63)^((kv&7)*8)]
  const int k_kvo = tid >> 3;
  const int k_d   = (((tid & 7) ^ ((tid >> 3) & 7)) * 8);
  // V staging: thread loads V row kv=lane, d slice vd = 32p + wave*8,
  // writes column pi(kv): pi = (b5)(b3 b2)(b4)(b1 b0)
  const int v_kv = lane;
  const int pv = (v_kv & 32) | (((v_kv >> 2) & 3) << 3) | (((v_kv >> 4) & 1) << 2) | (v_kv & 3);

  // Q fragments (SCALE*log2e folded in by the Q-GEMM epilogue)
  f16x8 qf[4][2];
#pragma unroll
  for (int m = 0; m < 4; ++m)
#pragma unroll
    for (int kb2 = 0; kb2 < 2; ++kb2)
      qf[m][kb2] = *(const f16x8*)(Qg + (rb + q0 + m * 16 + c) * DM + hc + kb2 * 32 + g * 8);

  f32x4 oT[4][4] = {};               // [db][m]; C col = q = c, row = d = g*4+r
  float dpart[4] = {0.f, 0.f, 0.f, 0.f};
  f16x8 vreg[2];

  auto stageK = [&](int t, int buf) {
    const int kv0 = t * 64;
#pragma unroll
    for (int p = 0; p < 2; ++p) {
      const int kv = kv0 + 32 * p + k_kvo;
      __builtin_amdgcn_global_load_lds(
          (const AS1 void*)(Kg + (rb + kv) * DM + hc + k_d),
          (AS3 void*)(&Kl[buf][p * 2048 + tid * 8]), 16, 0, 0);
    }
  };
  auto loadV = [&](int t) {
    const int kv0 = t * 64;
#pragma unroll
    for (int p = 0; p < 2; ++p)
      vreg[p] = *(const f16x8*)(Vg + (rb + kv0 + v_kv) * DM + hc + p * 32 + wave * 8);
  };
  auto writeV = [&](int buf) {
#pragma unroll
    for (int p = 0; p < 2; ++p) {
      const int vd = p * 32 + wave * 8;
      union { f16x8 v; unsigned short u[8]; } vv; vv.v = vreg[p];
#pragma unroll
      for (int j = 0; j < 8; ++j) Vt[buf][(vd + j) * 72 + pv] = vv.u[j];
    }
  };

  // prologue: tile 0 into buffer 0
  stageK(0, 0);
  loadV(0);
  writeV(0);
  __syncthreads();

  for (int t = 0; t < NT; ++t) {
    const int cur = t & 1;
    if (t + 1 < NT) { stageK(t + 1, cur ^ 1); loadV(t + 1); }

    const unsigned short* KL = Kl[cur];
    const unsigned short* VT = Vt[cur];

    // --- K fragments (shared across the 4 m-blocks) ---
    f16x8 kf[2][4];
#pragma unroll
    for (int kb2 = 0; kb2 < 2; ++kb2)
#pragma unroll
      for (int nb = 0; nb < 4; ++nb)
        kf[kb2][nb] = *(const f16x8*)(KL + (nb * 16 + c) * 64 + (((kb2 * 32 + g * 8) ^ ((c & 7) * 8))));
    // --- V^T fragments (shared across the 4 m-blocks) ---
    f16x8 vtf[2][4];
#pragma unroll
    for (int kb2 = 0; kb2 < 2; ++kb2)
#pragma unroll
      for (int db = 0; db < 4; ++db)
        vtf[kb2][db] = *(const f16x8*)(VT + (db * 16 + c) * 72 + kb2 * 32 + g * 8);

    // --- per m-block: S = QK^T -> fixed-shift signed softmax -> O += PV ---
#pragma unroll
    for (int m = 0; m < 4; ++m) {
      f32x4 s[4] = {};
#pragma unroll
      for (int nb = 0; nb < 4; ++nb)
#pragma unroll
        for (int kb2 = 0; kb2 < 2; ++kb2)
          s[nb] = __builtin_amdgcn_mfma_f32_16x16x32_f16(kf[kb2][nb], qf[m][kb2], s[nb], 0, 0, 0);

      // slot (kb2,g,j) <-> kv = 32*kb2 + 16*(j>>2) + 4*g + (j&3)
      union PW { f16x8 v; h16x2 w[4]; } pf[2];
      float es0 = 0.f, es1 = 0.f;
#pragma unroll
      for (int nb = 0; nb < 4; ++nb) {
        float p[4];
#pragma unroll
        for (int r = 0; r < 4; ++r) {
          const float sv = s[nb][r];
          const float e = exp2_fast(fabsf(sv) - 18.0f);
          if (r & 1) es1 += e; else es0 += e;
          p[r] = copysignf(e, sv);   // sign(S)*softmax(|S|)
        }
        pf[nb >> 1].w[(nb & 1) * 2]     = __builtin_amdgcn_cvt_pkrtz(p[0], p[1]);
        pf[nb >> 1].w[(nb & 1) * 2 + 1] = __builtin_amdgcn_cvt_pkrtz(p[2], p[3]);
      }
      dpart[m] += es0 + es1;

#pragma unroll
      for (int db = 0; db < 4; ++db) {
        oT[db][m] = __builtin_amdgcn_mfma_f32_16x16x32_f16(vtf[0][db], pf[0].v, oT[db][m], 0, 0, 0);
        oT[db][m] = __builtin_amdgcn_mfma_f32_16x16x32_f16(vtf[1][db], pf[1].v, oT[db][m], 0, 0, 0);
      }
    }

    if (t + 1 < NT) writeV(cur ^ 1);
    __syncthreads();
  }

  // --- denominator reduce (once) + normalize + store ---
  // lane holds O[q = m*16+c][d = db*16 + g*4 + r]
#pragma unroll
  for (int m = 0; m < 4; ++m) {
    float d = dpart[m];
    d += __shfl_xor(d, 16);
    d += __shfl_xor(d, 32);
    const float inv = 1.f / d;
#pragma unroll
    for (int db = 0; db < 4; ++db) {
      h16x2 h01 = __builtin_amdgcn_cvt_pkrtz(oT[db][m][0] * inv, oT[db][m][1] * inv);
      h16x2 h23 = __builtin_amdgcn_cvt_pkrtz(oT[db][m][2] * inv, oT[db][m][3] * inv);
      union { h16x2 h; unsigned u; } a, bb; a.h = h01; bb.h = h23;
      union { uint2 u2; unsigned u[2]; } st;
      st.u[0] = a.u; st.u[1] = bb.u;
      *(uint2*)(Og + (rb + q0 + m * 16 + c) * DM + hc + db * 16 + g * 4) = st.u2;
    }
  }
}

extern "C" void kernel_launch(void* const* d_in, const int* in_sizes, int n_in,
                              void* d_out, int out_size, void* d_ws, size_t ws_size,
                              hipStream_t stream) {
  const float* x  = (const float*)d_in[0];
  const float* Wq = (const float*)d_in[1];
  const float* bq = (const float*)d_in[2];
  const float* Wk = (const float*)d_in[3];
  const float* bk = (const float*)d_in[4];
  const float* Wv = (const float*)d_in[5];
  const float* bv = (const float*)d_in[6];
  const float* Wo = (const float*)d_in[7];
  const float* bo = (const float*)d_in[8];
  float* out = (float*)d_out;

  // workspace layout (f16 elements), total ~75.5 MB
  unsigned short* xb  = (unsigned short*)d_ws;                 // 8192*1024
  unsigned short* wqb = xb  + (size_t)MROWS * DM;              // 1024*1024 each
  unsigned short* wkb = wqb + (size_t)DM * DM;
  unsigned short* wvb = wkb + (size_t)DM * DM;
  unsigned short* wob = wvb + (size_t)DM * DM;
  unsigned short* qb  = wob + (size_t)DM * DM;                 // 8192*1024 each
  unsigned short* kb  = qb  + (size_t)MROWS * DM;
  unsigned short* vb  = kb  + (size_t)MROWS * DM;
  unsigned short* ab  = xb;  // reuse x region for attention output (x dead by then)

  cvt_all_kernel<<<(MROWS * DM / 4 + 4 * DM * DM / 4) / 256, 256, 0, stream>>>(
      x, Wq, Wk, Wv, Wo, xb, wqb, wkb, wvb, wob);

  // logits computed in exp2 domain: fold HD^-0.5 * log2(e) into Q
  const float SC = 0.125f * 1.4426950408889634f;
  gemm_qkv<<<dim3(DM / 128, MROWS / 128, 3), 256, 0, stream>>>(
      xb, wqb, wkb, wvb, bq, bk, bv, qb, kb, vb, SC);

  attn_kernel<<<dim3(NSEQ / 256, NB * NH), 256, 0, stream>>>(qb, kb, vb, ab);

  gemm_out<<<dim3(DM / 128, MROWS / 128), 256, 0, stream>>>(ab, wob, bo, out);
}